// Round 8
// baseline (1211.123 us; speedup 1.0000x reference)
//
#include <hip/hip_runtime.h>

typedef __attribute__((ext_vector_type(4))) float f32x4;
typedef __attribute__((ext_vector_type(4))) int i32x4;
typedef __attribute__((ext_vector_type(8))) short short8;
typedef __attribute__((ext_vector_type(4))) short short4v;
typedef unsigned short u16;
typedef unsigned int u32;
typedef unsigned long long u64;

#define DEV static __device__ __forceinline__

DEV float bf2f(u16 u){ union { unsigned int i; float f; } v; v.i = ((unsigned int)u) << 16; return v.f; }
DEV u16 f2bf(float f){ union { float f; unsigned int i; } v; v.f = f; unsigned int r = v.i + 0x7fffu + ((v.i >> 16) & 1u); return (u16)(r >> 16); }
DEV float sigm(float x){ return 1.f / (1.f + expf(-x)); }

// write-through (agent-coherent) stores
DEV void stg_f32(float* p, float v){ __hip_atomic_store(p, v, __ATOMIC_RELAXED, __HIP_MEMORY_SCOPE_AGENT); }
DEV void stg_u16(u16* p, u16 v){ __hip_atomic_store(p, v, __ATOMIC_RELAXED, __HIP_MEMORY_SCOPE_AGENT); }
DEV void stg_u32(u32* p, u32 v){ __hip_atomic_store(p, v, __ATOMIC_RELAXED, __HIP_MEMORY_SCOPE_AGENT); }
DEV void stg_u64(u64* p, u64 v){ __hip_atomic_store(p, v, __ATOMIC_RELAXED, __HIP_MEMORY_SCOPE_AGENT); }
DEV float ldg_f32(const float* p){ return __hip_atomic_load(p, __ATOMIC_RELAXED, __HIP_MEMORY_SCOPE_AGENT); }
// cache-bypassing 16B ops (issue only; caller does s_waitcnt + sched_barrier)
DEV void ldcc4i(i32x4* d, const void* p){
    asm volatile("global_load_dwordx4 %0, %1, off sc0 sc1" : "=v"(*d) : "v"(p) : "memory");
}
DEV void ldcc4f(f32x4* d, const void* p){
    asm volatile("global_load_dwordx4 %0, %1, off sc0 sc1" : "=v"(*d) : "v"(p) : "memory");
}
DEV void stcc4f(void* p, f32x4 v){
    asm volatile("global_store_dwordx4 %0, %1, off sc0 sc1" :: "v"(p), "v"(v) : "memory");
}
DEV short8 as_s8(i32x4 v){ union{ i32x4 i; short8 s; } u; u.i = v; return u.s; }

DEV short8 cvt8(const float* __restrict__ p){
    const f32x4* q = (const f32x4*)p;
    f32x4 lo = q[0], hi = q[1];
    short8 r;
    r[0]=(short)f2bf(lo[0]); r[1]=(short)f2bf(lo[1]); r[2]=(short)f2bf(lo[2]); r[3]=(short)f2bf(lo[3]);
    r[4]=(short)f2bf(hi[0]); r[5]=(short)f2bf(hi[1]); r[6]=(short)f2bf(hi[2]); r[7]=(short)f2bf(hi[3]);
    return r;
}
DEV u64 pack4bf(f32x4 a){
    union { short4v s; u64 q; } u;
    u.s[0]=(short)f2bf(a[0]); u.s[1]=(short)f2bf(a[1]);
    u.s[2]=(short)f2bf(a[2]); u.s[3]=(short)f2bf(a[3]);
    return u.q;
}
DEV u64 pack2f(float a, float b){ union{ float f[2]; u64 q; } u; u.f[0]=a; u.f[1]=b; return u.q; }

// ---------------------------------------------------------------------------
// barriers: slot-per-block; wave0 polls; no L2 invalidation anywhere.
// ---------------------------------------------------------------------------
DEV void bar_post(u32* __restrict__ slots, u32 n, int bid, int tid)
{
    asm volatile("s_waitcnt vmcnt(0)" ::: "memory");
    __syncthreads();
    if (tid == 0)
        __hip_atomic_store(&slots[bid], n, __ATOMIC_RELAXED, __HIP_MEMORY_SCOPE_AGENT);
}
DEV void bar_wait256(const u32* __restrict__ slots, u32 n, int tid)
{
    if (tid < 64) {
        for (;;) {
            bool ok = true;
#pragma unroll
            for (int c = 0; c < 4; ++c) {
                u32 v = __hip_atomic_load(&slots[tid*4+c], __ATOMIC_RELAXED, __HIP_MEMORY_SCOPE_AGENT);
                ok &= (v >= n);
            }
            if (__all(ok)) break;
            __builtin_amdgcn_s_sleep(8);
        }
    }
    __syncthreads();
}
DEV void bar_wait64(const u32* __restrict__ slots, u32 n, int tid)
{
    if (tid < 64) {
        for (;;) {
            u32 v = __hip_atomic_load(&slots[tid], __ATOMIC_RELAXED, __HIP_MEMORY_SCOPE_AGENT);
            if (__all(v >= n)) break;
            __builtin_amdgcn_s_sleep(1);
        }
    }
    __syncthreads();
}

// ---------------------------------------------------------------------------
// k_all: everything in one cooperative kernel. 256 blocks x 256 threads.
// LDS: [0,128K) Wlds (A, swizzled W_hh) | red at 128K (A, [2][32][66] f32)
//      B blocks reuse [0,..): hB[1024] f32, scb[32], pb[32]
// ---------------------------------------------------------------------------
#define WLDS_BYTES 131072
#define RED_PITCH 66
#define DYN_BYTES (WLDS_BYTES + 2*32*RED_PITCH*4)

__global__ void __launch_bounds__(256, 1)
k_all(const int* __restrict__ tgt, const float* __restrict__ h0, const float* __restrict__ c0,
      const float* __restrict__ enc, const int* __restrict__ slen, const float* __restrict__ emb,
      const float* __restrict__ Wih, const float* __restrict__ Whh,
      const float* __restrict__ bih, const float* __restrict__ bhh,
      const float* __restrict__ Wai, const float* __restrict__ Wao,
      float* __restrict__ out,
      u16* __restrict__ Wih16, u16* __restrict__ Wao16, u16* __restrict__ enc16,
      u16* __restrict__ xrow, u16* __restrict__ WT, u16* __restrict__ xg2,
      float* __restrict__ Mf, u16* __restrict__ hb, float* __restrict__ hAllF,
      u16* __restrict__ hAll, u16* __restrict__ ctxA,
      float* __restrict__ pCtx, float* __restrict__ pMx, float* __restrict__ pSm,
      u32* __restrict__ bar)
{
    const int bid = blockIdx.x, tid = threadIdx.x;
    const int wv = tid >> 6, l = tid & 63, lr = l & 15, lq = l >> 4;
    u32* slots = bar;

    extern __shared__ char smem[];
    float* red = (float*)(smem + WLDS_BYTES);      // [2][32][RED_PITCH]
    float* hB  = (float*)smem;                     // B: [1024]
    float* scb = (float*)(smem + 4096);            // B: [32]
    float* pb  = (float*)(smem + 4096 + 128);      // B: [32]
    u16 (*tl)[65] = (u16(*)[65])smem;              // prep transpose tile

    // ================= P0: prep (49 units per block) =================
    for (int u = bid; u < 12544; u += 256) {
        if (u < 10240) {
            const float* src; u16* dst; size_t i;
            if (u < 4096)      { src = Wih; dst = Wih16; i = (size_t)u * 1024 + tid * 4; }
            else if (u < 6144) { src = Wao; dst = Wao16; i = (size_t)(u - 4096) * 1024 + tid * 4; }
            else               { src = enc; dst = enc16; i = (size_t)(u - 6144) * 1024 + tid * 4; }
            f32x4 v = *(const f32x4*)(src + i);
            stg_u64((u64*)(dst + i), pack4bf(v));
        } else if (u < 12256) {
            int r = u - 10240;
            int t = r >> 5, b = r & 31;
            const float* src = emb + (size_t)tgt[b * 64 + t] * 1024;
            f32x4 v = *(const f32x4*)(src + tid * 4);
            stg_u64((u64*)(xrow + (size_t)r * 1024 + tid * 4), pack4bf(v));
        } else if (u < 12512) {
            int tb = u - 12256;
            int ti = tb >> 4, tj = tb & 15;
            int rr = tid >> 2, cc = (tid & 3) * 16;
            __syncthreads();
            for (int i = 0; i < 16; ++i)
                tl[rr][cc + i] = f2bf(Wai[(size_t)(ti * 64 + rr) * 1024 + tj * 64 + cc + i]);
            __syncthreads();
            for (int i4 = 0; i4 < 4; ++i4) {
                union { u16 s[4]; u64 q; } o;
#pragma unroll
                for (int k = 0; k < 4; ++k) o.s[k] = tl[cc + i4 * 4 + k][rr];
                stg_u64((u64*)(WT + (size_t)(tj * 64 + rr) * 1024 + ti * 64 + cc + i4 * 4), o.q);
            }
        } else {
            int b = u - 12512;
            int j = tid * 4;
            union { u16 s[4]; u64 q; } o;
#pragma unroll
            for (int i = 0; i < 4; ++i) {
                int k = j + i;
                float hv = (k < 512) ? h0[(size_t)b * 512 + k] : h0[(size_t)(32 + b) * 512 + (k - 512)];
                o.s[i] = f2bf(hv);
            }
            stg_u64((u64*)(hb + (size_t)b * 1024 + j), o.q);   // slot 0 = h_0
        }
    }
    bar_post(slots, 1, bid, tid);
    bar_wait256(slots, 1, tid);

    // ================= P1: xg-GEMM (2048 tiles) + M-GEMM (1024 tiles) =================
    for (int tile = bid; tile < 3072; tile += 256) {
        if (tile < 2048) {
            const int mt = tile & 31, nt = tile >> 5;
            const int r0 = mt * 64 + wv * 16, n0 = nt * 64;
            int rr0 = r0 + lr; int rc = (rr0 < 2016) ? rr0 : 2015;
            const u16* arow = xrow + (size_t)rc * 1024;
            const u16* brow = Wih16 + (size_t)(n0 + lr) * 1024;
            f32x4 acc[4] = {{0,0,0,0},{0,0,0,0},{0,0,0,0},{0,0,0,0}};
            for (int k0 = 0; k0 < 1024; k0 += 32) {
                int ko = k0 + lq * 8;
                short8 av = *(const short8*)(arow + ko);
#pragma unroll
                for (int nf = 0; nf < 4; ++nf) {
                    short8 bv = *(const short8*)(brow + (size_t)nf * 16 * 1024 + ko);
                    acc[nf] = __builtin_amdgcn_mfma_f32_16x16x32_bf16(av, bv, acc[nf], 0, 0, 0);
                }
            }
#pragma unroll
            for (int nf = 0; nf < 4; ++nf) {
                int n = n0 + nf * 16 + lr;
                float bias = bih[n] + bhh[n];
                int gate = n >> 10, hc = n & 1023;
#pragma unroll
                for (int q = 0; q < 4; ++q) {
                    int rr = r0 + lq * 4 + q;
                    if (rr < 2016)
                        stg_u16(&xg2[((size_t)rr * 1024 + hc) * 4 + gate], f2bf(acc[nf][q] + bias));
                }
            }
        } else {
            const int mb = tile - 2048;
            const int mt = mb & 63, nt = mb >> 6;
            const int r0 = mt * 64 + wv * 16, n0 = nt * 64;
            const u16* arow = enc16 + (size_t)(r0 + lr) * 1024;
            const u16* brow = WT + (size_t)(n0 + lr) * 1024;
            f32x4 acc[4] = {{0,0,0,0},{0,0,0,0},{0,0,0,0},{0,0,0,0}};
            for (int k0 = 0; k0 < 1024; k0 += 32) {
                int ko = k0 + lq * 8;
                short8 av = *(const short8*)(arow + ko);
#pragma unroll
                for (int nf = 0; nf < 4; ++nf) {
                    short8 bv = *(const short8*)(brow + (size_t)nf * 16 * 1024 + ko);
                    acc[nf] = __builtin_amdgcn_mfma_f32_16x16x32_bf16(av, bv, acc[nf], 0, 0, 0);
                }
            }
#pragma unroll
            for (int nf = 0; nf < 4; ++nf) {
                int n = n0 + nf * 16 + lr;
#pragma unroll
                for (int q = 0; q < 4; ++q)
                    stg_f32(&Mf[(size_t)(r0 + lq * 4 + q) * 1024 + n], acc[nf][q]);
            }
        }
    }
    bar_post(slots, 2, bid, tid);
    bar_wait256(slots, 2, tid);

    // ================= serial loop =================
    if (bid < 64) {
        // -------- group A: gates GEMM + LSTM, 64-block barrier domain --------
        const int g = bid;
        // stage W_hh -> LDS (swizzled), rows n=gate*16+j
        for (int u = tid; u < 8192; u += 256) {
            int row = u >> 7, c16 = u & 127;
            const float* src = Whh + ((size_t)((row >> 4) * 1024 + g * 16 + (row & 15))) * 1024 + c16 * 8;
            short8 w = cvt8(src);
            int byte = (row * 2048 + c16 * 16) ^ ((row & 7) << 4);
            *(short8*)(smem + byte) = w;
        }
        // LSTM locals: thread -> cells (b, jp), (b, jp+1); hc = g*16+jp
        const int b = tid >> 3, jp = (tid & 7) * 2;
        const int hc = g * 16 + jp;
        float creg0 = (hc < 512) ? c0[(size_t)b * 512 + hc] : c0[(size_t)(32 + b) * 512 + hc - 512];
        float creg1 = (hc + 1 < 512) ? c0[(size_t)b * 512 + hc + 1] : c0[(size_t)(32 + b) * 512 + hc + 1 - 512];
        float xga[4], xgb[4];
        {
            f32x4 raw = *(const f32x4*)(xg2 + ((size_t)b * 1024 + hc) * 4);   // t=0
            union { f32x4 f; short8 s; } u; u.f = raw;
#pragma unroll
            for (int gt = 0; gt < 4; ++gt) { xga[gt] = bf2f((u16)u.s[gt]); xgb[gt] = bf2f((u16)u.s[4 + gt]); }
        }
        const int kw = wv & 1, nw = wv >> 1;       // K-half, N-half per wave
        __syncthreads();

        for (int t = 0; t < 63; ++t) {
            if (t > 0) bar_wait64(slots, (u32)(t + 2), tid);

            // ---- GEMM: 32 batches x 64 gate-cols, K=1024 (this wave: K-half kw, N-half nw)
            const u16* hbase = hb + (size_t)(t & 1) * 32768;
            const u16* p0 = hbase + (size_t)lr * 1024 + kw * 512 + lq * 8;
            const u16* p1 = p0 + 16 * 1024;
            i32x4 ap0[8], ap1[8];
#pragma unroll
            for (int p = 0; p < 8; ++p) { ldcc4i(&ap0[p], p0 + p * 32); ldcc4i(&ap1[p], p1 + p * 32); }
            f32x4 acc00 = {0,0,0,0}, acc01 = {0,0,0,0}, acc10 = {0,0,0,0}, acc11 = {0,0,0,0};
#pragma unroll
            for (int ks = 0; ks < 16; ++ks) {
                // B frags from swizzled LDS
                int n0r = nw * 32 + lr;
                int kbyte = (kw * 512 + ks * 32 + lq * 8) * 2;
                short8 bv0 = *(const short8*)(smem + ((n0r * 2048 + kbyte) ^ ((n0r & 7) << 4)));
                int n1r = n0r + 16;
                short8 bv1 = *(const short8*)(smem + ((n1r * 2048 + kbyte) ^ ((n1r & 7) << 4)));
                if (ks <= 8) { asm volatile("s_waitcnt vmcnt(14)" ::: "memory"); }
                else         { asm volatile("s_waitcnt vmcnt(%0)" :: "i"(2 * (15 - ks)) : "memory"); }
                __builtin_amdgcn_sched_barrier(0);
                short8 a0 = as_s8(ap0[ks & 7]), a1 = as_s8(ap1[ks & 7]);
                acc00 = __builtin_amdgcn_mfma_f32_16x16x32_bf16(a0, bv0, acc00, 0, 0, 0);
                acc10 = __builtin_amdgcn_mfma_f32_16x16x32_bf16(a1, bv0, acc10, 0, 0, 0);
                acc01 = __builtin_amdgcn_mfma_f32_16x16x32_bf16(a0, bv1, acc01, 0, 0, 0);
                acc11 = __builtin_amdgcn_mfma_f32_16x16x32_bf16(a1, bv1, acc11, 0, 0, 0);
                if (ks < 8) { ldcc4i(&ap0[ks & 7], p0 + (ks + 8) * 32); ldcc4i(&ap1[ks & 7], p1 + (ks + 8) * 32); }
            }
#pragma unroll
            for (int q = 0; q < 4; ++q) {
                red[(kw * 32 + lq * 4 + q) * RED_PITCH + nw * 32 + lr]       = acc00[q];
                red[(kw * 32 + 16 + lq * 4 + q) * RED_PITCH + nw * 32 + lr]  = acc10[q];
                red[(kw * 32 + lq * 4 + q) * RED_PITCH + nw * 32 + 16 + lr]      = acc01[q];
                red[(kw * 32 + 16 + lq * 4 + q) * RED_PITCH + nw * 32 + 16 + lr] = acc11[q];
            }
            __syncthreads();

            // ---- LSTM (2 cells/thread)
            float G0[4], G1[4];
#pragma unroll
            for (int gt = 0; gt < 4; ++gt) {
                int n = gt * 16 + jp;
                G0[gt] = red[b * RED_PITCH + n] + red[(32 + b) * RED_PITCH + n] + xga[gt];
                G1[gt] = red[b * RED_PITCH + n + 1] + red[(32 + b) * RED_PITCH + n + 1] + xgb[gt];
            }
            float cn0 = sigm(G0[1]) * creg0 + sigm(G0[0]) * tanhf(G0[2]);
            float hn0 = sigm(G0[3]) * tanhf(cn0);
            float cn1 = sigm(G1[1]) * creg1 + sigm(G1[0]) * tanhf(G1[2]);
            float hn1 = sigm(G1[3]) * tanhf(cn1);
            creg0 = cn0; creg1 = cn1;
            u16 hb0 = f2bf(hn0), hb1 = f2bf(hn1);
            u32 hpair = (u32)hb0 | ((u32)hb1 << 16);
            stg_u32((u32*)&hb[(size_t)((t + 1) & 1) * 32768 + b * 1024 + hc], hpair);
            stg_u32((u32*)&hAll[((size_t)t * 32 + b) * 1024 + hc], hpair);
            stg_u64((u64*)&hAllF[((size_t)t * 32 + b) * 1024 + hc], pack2f(hn0, hn1));
            if (t == 62)
                stg_u64((u64*)&out[2064384 + b * 1024 + hc], pack2f(hn0, hn1));

            bar_post(slots, (u32)(t + 3), bid, tid);
            __syncthreads();   // red reuse protection

            // shadow: prefetch next xg
            if (t < 62) {
                f32x4 raw = *(const f32x4*)(xg2 + ((size_t)((t + 1) * 32 + b) * 1024 + hc) * 4);
                union { f32x4 f; short8 s; } u; u.f = raw;
#pragma unroll
                for (int gt = 0; gt < 4; ++gt) { xga[gt] = bf2f((u16)u.s[gt]); xgb[gt] = bf2f((u16)u.s[4 + gt]); }
            }
        }
        // final c
        stg_u64((u64*)&out[2064384 + 32768 + b * 1024 + hc], pack2f(creg0, creg1));
    } else if (bid < 192) {
        // -------- group B: attention chunks, no barrier (trails group A) --------
        const int idx = bid - 64;
        const int b = idx >> 2, q = idx & 3;
        int vlen = slen[b]; if (vlen < 1) vlen = 1;
        const int tj = l & 15, sg4 = l >> 4;
        for (int s = 0; s < 63; ++s) {
            bar_wait64(slots, (u32)(s + 3), tid);       // h_{s+1} visible
            {   // stage h into LDS
                f32x4 hv;
                ldcc4f(&hv, hAllF + ((size_t)s * 32 + b) * 1024 + tid * 4);
                asm volatile("s_waitcnt vmcnt(0)" ::: "memory");
                __builtin_amdgcn_sched_barrier(0);
                *(f32x4*)&hB[tid * 4] = hv;
            }
            __syncthreads();
            // scores: wave wv rows [wv*8, wv*8+8)
#pragma unroll
            for (int rr2 = 0; rr2 < 2; ++rr2) {
                int lrow = wv * 8 + rr2 * 4 + sg4;
                const float* Mrow = Mf + ((size_t)(b * 128 + q * 32 + lrow)) * 1024;
                float sc = 0.f;
#pragma unroll
                for (int it = 0; it < 16; ++it) {
                    int j = it * 64 + tj * 4;
                    f32x4 m4 = *(const f32x4*)(Mrow + j);
                    f32x4 h4 = *(const f32x4*)&hB[j];
                    sc += m4[0]*h4[0] + m4[1]*h4[1] + m4[2]*h4[2] + m4[3]*h4[3];
                }
                sc += __shfl_xor(sc, 1);
                sc += __shfl_xor(sc, 2);
                sc += __shfl_xor(sc, 4);
                sc += __shfl_xor(sc, 8);
                if (tj == 0) scb[lrow] = (q * 32 + lrow < vlen) ? sc : -1e30f;
            }
            __syncthreads();
            if (tid < 64) {   // wave0: chunk partial softmax
                float a = (tid < 32) ? scb[tid] : -1e30f;
                float m = a;
#pragma unroll
                for (int d = 1; d < 64; d <<= 1) m = fmaxf(m, __shfl_xor(m, d));
                float e = (tid < 32 && a > -1e29f) ? expf(a - m) : 0.f;
                float ssum = e;
#pragma unroll
                for (int d = 1; d < 64; d <<= 1) ssum += __shfl_xor(ssum, d);
                if (tid < 32) pb[tid] = e;
                if (tid == 0) {
                    stg_f32(&pMx[((size_t)s * 32 + b) * 4 + q], m);
                    stg_f32(&pSm[((size_t)s * 32 + b) * 4 + q], ssum);
                }
            }
            __syncthreads();
            // ctx partial (unnormalized)
            f32x4 ca = {0.f, 0.f, 0.f, 0.f};
            const u16* eb = enc16 + ((size_t)(b * 128 + q * 32)) * 1024 + tid * 4;
#pragma unroll
            for (int r = 0; r < 32; ++r) {
                float p = pb[r];
                short4v e4 = *(const short4v*)(eb + (size_t)r * 1024);
                ca[0] += p * bf2f((u16)e4[0]);
                ca[1] += p * bf2f((u16)e4[1]);
                ca[2] += p * bf2f((u16)e4[2]);
                ca[3] += p * bf2f((u16)e4[3]);
            }
            stcc4f(pCtx + (((size_t)s * 32 + b) * 4 + q) * 1024 + tid * 4, ca);
        }
    }
    bar_post(slots, 66, bid, tid);
    bar_wait256(slots, 66, tid);

    // ================= P2a: combine chunk partials -> ctxA =================
    for (int r = bid; r < 2016; r += 256) {
        float m4[4], s4[4];
#pragma unroll
        for (int c = 0; c < 4; ++c) { m4[c] = ldg_f32(pMx + (size_t)r * 4 + c); s4[c] = ldg_f32(pSm + (size_t)r * 4 + c); }
        float gm = fmaxf(fmaxf(m4[0], m4[1]), fmaxf(m4[2], m4[3]));
        float e[4], ws = 0.f;
#pragma unroll
        for (int c = 0; c < 4; ++c) { e[c] = expf(m4[c] - gm); ws += s4[c] * e[c]; }
        float inv = 1.f / ws;
        f32x4 pc[4];
#pragma unroll
        for (int c = 0; c < 4; ++c) ldcc4f(&pc[c], pCtx + ((size_t)r * 4 + c) * 1024 + tid * 4);
        asm volatile("s_waitcnt vmcnt(0)" ::: "memory");
        __builtin_amdgcn_sched_barrier(0);
        f32x4 a = {0.f, 0.f, 0.f, 0.f};
#pragma unroll
        for (int c = 0; c < 4; ++c) {
            float sc = e[c] * inv;
            a[0] += pc[c][0] * sc; a[1] += pc[c][1] * sc; a[2] += pc[c][2] * sc; a[3] += pc[c][3] * sc;
        }
        stg_u64((u64*)(ctxA + (size_t)r * 1024 + tid * 4), pack4bf(a));
    }
    bar_post(slots, 67, bid, tid);
    bar_wait256(slots, 67, tid);

    // ================= P2b: output GEMM (512 tiles, 2 per block) =================
    for (int tile = bid; tile < 512; tile += 256) {
        const int mt = tile & 31, nt = tile >> 5;
        const int r0 = mt * 64 + wv * 16, n0 = nt * 64;
        int rr0 = r0 + lr; int rc = (rr0 < 2016) ? rr0 : 2015;
        const u16* arc = ctxA + (size_t)rc * 1024;
        const u16* arh = hAll + (size_t)rc * 1024;
        const u16* brow = Wao16 + (size_t)(n0 + lr) * 2048;
        f32x4 acc[4] = {{0,0,0,0},{0,0,0,0},{0,0,0,0},{0,0,0,0}};
        for (int k0 = 0; k0 < 2048; k0 += 32) {
            int ko = k0 + lq * 8;
            short8 av = (k0 < 1024) ? *(const short8*)(arc + ko)
                                    : *(const short8*)(arh + (ko - 1024));
#pragma unroll
            for (int nf = 0; nf < 4; ++nf) {
                short8 bv = *(const short8*)(brow + (size_t)nf * 16 * 2048 + ko);
                acc[nf] = __builtin_amdgcn_mfma_f32_16x16x32_bf16(av, bv, acc[nf], 0, 0, 0);
            }
        }
#pragma unroll
        for (int nf = 0; nf < 4; ++nf) {
            int n = n0 + nf * 16 + lr;
#pragma unroll
            for (int q = 0; q < 4; ++q) {
                int rr = r0 + lq * 4 + q;
                if (rr < 2016) {
                    int t = rr >> 5, b = rr & 31;
                    out[(size_t)b * 64512 + t * 1024 + n] = tanhf(acc[nf][q]);
                }
            }
        }
    }
}

// ---------------------------------------------------------------------------
extern "C" void kernel_launch(void* const* d_in, const int* in_sizes, int n_in,
                              void* d_out, int out_size, void* d_ws, size_t ws_size,
                              hipStream_t stream)
{
    (void)in_sizes; (void)n_in; (void)out_size; (void)ws_size;
    const int*   tgt  = (const int*)d_in[0];
    const float* h0   = (const float*)d_in[1];
    const float* c0   = (const float*)d_in[2];
    const float* enc  = (const float*)d_in[3];
    const int*   slen = (const int*)d_in[4];
    const float* emb  = (const float*)d_in[5];
    const float* Wih  = (const float*)d_in[6];
    const float* Whh  = (const float*)d_in[7];
    const float* bih  = (const float*)d_in[8];
    const float* bhh  = (const float*)d_in[9];
    const float* Wai  = (const float*)d_in[10];
    const float* Wao  = (const float*)d_in[11];
    float* out = (float*)d_out;

    char* ws = (char*)d_ws;
    size_t off = 0;
    auto alloc = [&](size_t bytes) -> char* {
        char* p = ws + off; off += (bytes + 255) & ~(size_t)255; return p;
    };
    u16*   Wih16 = (u16*)  alloc(4096UL * 1024 * 2);
    u16*   Wao16 = (u16*)  alloc(1024UL * 2048 * 2);
    u16*   enc16 = (u16*)  alloc(4096UL * 1024 * 2);
    u16*   xrow  = (u16*)  alloc(2016UL * 1024 * 2);
    u16*   WT    = (u16*)  alloc(1024UL * 1024 * 2);
    u16*   xg2   = (u16*)  alloc(2016UL * 1024 * 4 * 2);
    float* Mf    = (float*)alloc(4096UL * 1024 * 4);
    u16*   hb    = (u16*)  alloc(2UL * 32 * 1024 * 2);
    float* hAllF = (float*)alloc(2016UL * 1024 * 4);
    u16*   hAll  = (u16*)  alloc(2016UL * 1024 * 2);
    u16*   ctxA  = (u16*)  alloc(2016UL * 1024 * 2);
    float* pCtx  = (float*)alloc(2016UL * 4 * 1024 * 4);
    float* pMx   = (float*)alloc(2016UL * 4 * 4);
    float* pSm   = (float*)alloc(2016UL * 4 * 4);
    u32*   bar   = (u32*)  alloc(2048);

    static int lds_set = 0;
    if (!lds_set) {
        (void)hipFuncSetAttribute((const void*)k_all,
                                  hipFuncAttributeMaxDynamicSharedMemorySize, DYN_BYTES);
        lds_set = 1;
    }

    hipMemsetAsync(bar, 0, 2048, stream);
    void* kargs[] = { (void*)&tgt, (void*)&h0, (void*)&c0, (void*)&enc, (void*)&slen, (void*)&emb,
                      (void*)&Wih, (void*)&Whh, (void*)&bih, (void*)&bhh, (void*)&Wai, (void*)&Wao,
                      (void*)&out,
                      (void*)&Wih16, (void*)&Wao16, (void*)&enc16, (void*)&xrow, (void*)&WT,
                      (void*)&xg2, (void*)&Mf, (void*)&hb, (void*)&hAllF, (void*)&hAll, (void*)&ctxA,
                      (void*)&pCtx, (void*)&pMx, (void*)&pSm, (void*)&bar };
    hipLaunchCooperativeKernel((const void*)k_all, dim3(256), dim3(256), kargs, DYN_BYTES, stream);
}

// Round 9
// 944.105 us; speedup vs baseline: 1.2828x; 1.2828x over previous
//
#include <hip/hip_runtime.h>

typedef __attribute__((ext_vector_type(4))) float f32x4;
typedef __attribute__((ext_vector_type(4))) int i32x4;
typedef __attribute__((ext_vector_type(8))) short short8;
typedef __attribute__((ext_vector_type(4))) short short4v;
typedef unsigned short u16;
typedef unsigned int u32;
typedef unsigned long long u64;

#define DEV static __device__ __forceinline__

DEV float bf2f(u16 u){ union { unsigned int i; float f; } v; v.i = ((unsigned int)u) << 16; return v.f; }
DEV u16 f2bf(float f){ union { float f; unsigned int i; } v; v.f = f; unsigned int r = v.i + 0x7fffu + ((v.i >> 16) & 1u); return (u16)(r >> 16); }
DEV float sigm(float x){ return 1.f / (1.f + expf(-x)); }

// write-through (agent-coherent) stores
DEV void stg_f32(float* p, float v){ __hip_atomic_store(p, v, __ATOMIC_RELAXED, __HIP_MEMORY_SCOPE_AGENT); }
DEV void stg_u16(u16* p, u16 v){ __hip_atomic_store(p, v, __ATOMIC_RELAXED, __HIP_MEMORY_SCOPE_AGENT); }
DEV void stg_u32(u32* p, u32 v){ __hip_atomic_store(p, v, __ATOMIC_RELAXED, __HIP_MEMORY_SCOPE_AGENT); }
DEV void stg_u64(u64* p, u64 v){ __hip_atomic_store(p, v, __ATOMIC_RELAXED, __HIP_MEMORY_SCOPE_AGENT); }
DEV float ldg_f32(const float* p){ return __hip_atomic_load(p, __ATOMIC_RELAXED, __HIP_MEMORY_SCOPE_AGENT); }
// cache-bypassing 16B ops (issue only; caller does s_waitcnt + sched_barrier)
DEV void ldcc4i(i32x4* d, const void* p){
    asm volatile("global_load_dwordx4 %0, %1, off sc0 sc1" : "=v"(*d) : "v"(p) : "memory");
}
DEV void ldcc4f(f32x4* d, const void* p){
    asm volatile("global_load_dwordx4 %0, %1, off sc0 sc1" : "=v"(*d) : "v"(p) : "memory");
}
DEV void stcc4f(void* p, f32x4 v){
    asm volatile("global_store_dwordx4 %0, %1, off sc0 sc1" :: "v"(p), "v"(v) : "memory");
}
DEV short8 as_s8(i32x4 v){ union{ i32x4 i; short8 s; } u; u.i = v; return u.s; }

DEV short8 cvt8(const float* __restrict__ p){
    const f32x4* q = (const f32x4*)p;
    f32x4 lo = q[0], hi = q[1];
    short8 r;
    r[0]=(short)f2bf(lo[0]); r[1]=(short)f2bf(lo[1]); r[2]=(short)f2bf(lo[2]); r[3]=(short)f2bf(lo[3]);
    r[4]=(short)f2bf(hi[0]); r[5]=(short)f2bf(hi[1]); r[6]=(short)f2bf(hi[2]); r[7]=(short)f2bf(hi[3]);
    return r;
}
DEV u64 pack4bf(f32x4 a){
    union { short4v s; u64 q; } u;
    u.s[0]=(short)f2bf(a[0]); u.s[1]=(short)f2bf(a[1]);
    u.s[2]=(short)f2bf(a[2]); u.s[3]=(short)f2bf(a[3]);
    return u.q;
}
DEV u64 pack2f(float a, float b){ union{ float f[2]; u64 q; } u; u.f[0]=a; u.f[1]=b; return u.q; }

// ---------------------------------------------------------------------------
// barriers: slot-per-block; wave0 polls; no L2 invalidation anywhere.
// ---------------------------------------------------------------------------
DEV void bar_post(u32* __restrict__ slots, u32 n, int bid, int tid)
{
    asm volatile("s_waitcnt vmcnt(0)" ::: "memory");
    __syncthreads();
    if (tid == 0)
        __hip_atomic_store(&slots[bid], n, __ATOMIC_RELAXED, __HIP_MEMORY_SCOPE_AGENT);
}
DEV void bar_wait256(const u32* __restrict__ slots, u32 n, int tid)
{
    if (tid < 64) {
        for (;;) {
            bool ok = true;
#pragma unroll
            for (int c = 0; c < 4; ++c) {
                u32 v = __hip_atomic_load(&slots[tid*4+c], __ATOMIC_RELAXED, __HIP_MEMORY_SCOPE_AGENT);
                ok &= (v >= n);
            }
            if (__all(ok)) break;
            __builtin_amdgcn_s_sleep(8);
        }
    }
    __syncthreads();
}
DEV void bar_wait64(const u32* __restrict__ slots, u32 n, int tid)
{
    if (tid < 64) {
        for (;;) {
            u32 v = __hip_atomic_load(&slots[tid], __ATOMIC_RELAXED, __HIP_MEMORY_SCOPE_AGENT);
            if (__all(v >= n)) break;
            __builtin_amdgcn_s_sleep(1);
        }
    }
    __syncthreads();
}

// ---------------------------------------------------------------------------
// k_all: everything in one cooperative kernel. 256 blocks x 256 threads.
// LDS (A blocks):  [0,128K) swizzled W_hh | red at 128K ([2][32][66] f32)
// LDS (B blocks):  [0,132096) Ml fp32 [32][1032] | hB | scb | pb
// ---------------------------------------------------------------------------
#define WLDS_BYTES 131072
#define RED_PITCH 66
#define MLB_PITCH 1032
#define MLB_BYTES (32 * MLB_PITCH * 4)
#define DYN_BYTES (WLDS_BYTES + 2*32*RED_PITCH*4)

__global__ void __launch_bounds__(256, 1)
k_all(const int* __restrict__ tgt, const float* __restrict__ h0, const float* __restrict__ c0,
      const float* __restrict__ enc, const int* __restrict__ slen, const float* __restrict__ emb,
      const float* __restrict__ Wih, const float* __restrict__ Whh,
      const float* __restrict__ bih, const float* __restrict__ bhh,
      const float* __restrict__ Wai, const float* __restrict__ Wao,
      float* __restrict__ out,
      u16* __restrict__ Wih16, u16* __restrict__ Wao16, u16* __restrict__ enc16,
      u16* __restrict__ xrow, u16* __restrict__ WT, u16* __restrict__ xg2,
      float* __restrict__ Mf, u16* __restrict__ hb, float* __restrict__ hAllF,
      u16* __restrict__ hAll, u16* __restrict__ ctxA,
      float* __restrict__ pCtx, float* __restrict__ pMx, float* __restrict__ pSm,
      u32* __restrict__ bar)
{
    const int bid = blockIdx.x, tid = threadIdx.x;
    const int wv = tid >> 6, l = tid & 63, lr = l & 15, lq = l >> 4;
    u32* slots = bar;

    extern __shared__ char smem[];
    float* red = (float*)(smem + WLDS_BYTES);        // A: [2][32][RED_PITCH]
    float* MlB = (float*)smem;                       // B: [32][MLB_PITCH]
    float* hB  = (float*)(smem + MLB_BYTES);         // B: [1024]
    float* scb = (float*)(smem + MLB_BYTES + 4096);  // B: [32]
    float* pb  = (float*)(smem + MLB_BYTES + 4096 + 128); // B: [32]
    u16 (*tl)[65] = (u16(*)[65])smem;                // prep transpose tile

    // ================= P0: prep (49 units per block) =================
    for (int u = bid; u < 12544; u += 256) {
        if (u < 10240) {
            const float* src; u16* dst; size_t i;
            if (u < 4096)      { src = Wih; dst = Wih16; i = (size_t)u * 1024 + tid * 4; }
            else if (u < 6144) { src = Wao; dst = Wao16; i = (size_t)(u - 4096) * 1024 + tid * 4; }
            else               { src = enc; dst = enc16; i = (size_t)(u - 6144) * 1024 + tid * 4; }
            f32x4 v = *(const f32x4*)(src + i);
            stg_u64((u64*)(dst + i), pack4bf(v));
        } else if (u < 12256) {
            int r = u - 10240;
            int t = r >> 5, b = r & 31;
            const float* src = emb + (size_t)tgt[b * 64 + t] * 1024;
            f32x4 v = *(const f32x4*)(src + tid * 4);
            stg_u64((u64*)(xrow + (size_t)r * 1024 + tid * 4), pack4bf(v));
        } else if (u < 12512) {
            int tb = u - 12256;
            int ti = tb >> 4, tj = tb & 15;
            int rr = tid >> 2, cc = (tid & 3) * 16;
            __syncthreads();
            for (int i = 0; i < 16; ++i)
                tl[rr][cc + i] = f2bf(Wai[(size_t)(ti * 64 + rr) * 1024 + tj * 64 + cc + i]);
            __syncthreads();
            for (int i4 = 0; i4 < 4; ++i4) {
                union { u16 s[4]; u64 q; } o;
#pragma unroll
                for (int k = 0; k < 4; ++k) o.s[k] = tl[cc + i4 * 4 + k][rr];
                stg_u64((u64*)(WT + (size_t)(tj * 64 + rr) * 1024 + ti * 64 + cc + i4 * 4), o.q);
            }
        } else {
            int b = u - 12512;
            int j = tid * 4;
            union { u16 s[4]; u64 q; } o;
#pragma unroll
            for (int i = 0; i < 4; ++i) {
                int k = j + i;
                float hv = (k < 512) ? h0[(size_t)b * 512 + k] : h0[(size_t)(32 + b) * 512 + (k - 512)];
                o.s[i] = f2bf(hv);
            }
            stg_u64((u64*)(hb + (size_t)b * 1024 + j), o.q);   // slot 0 = h_0
        }
    }
    bar_post(slots, 1, bid, tid);
    bar_wait256(slots, 1, tid);

    // ================= P1: xg-GEMM (2048 tiles) + M-GEMM (1024 tiles) =================
    for (int tile = bid; tile < 3072; tile += 256) {
        if (tile < 2048) {
            const int mt = tile & 31, nt = tile >> 5;
            const int r0 = mt * 64 + wv * 16, n0 = nt * 64;
            int rr0 = r0 + lr; int rc = (rr0 < 2016) ? rr0 : 2015;
            const u16* arow = xrow + (size_t)rc * 1024;
            const u16* brow = Wih16 + (size_t)(n0 + lr) * 1024;
            f32x4 acc[4] = {{0,0,0,0},{0,0,0,0},{0,0,0,0},{0,0,0,0}};
            for (int k0 = 0; k0 < 1024; k0 += 32) {
                int ko = k0 + lq * 8;
                short8 av = *(const short8*)(arow + ko);
#pragma unroll
                for (int nf = 0; nf < 4; ++nf) {
                    short8 bv = *(const short8*)(brow + (size_t)nf * 16 * 1024 + ko);
                    acc[nf] = __builtin_amdgcn_mfma_f32_16x16x32_bf16(av, bv, acc[nf], 0, 0, 0);
                }
            }
#pragma unroll
            for (int nf = 0; nf < 4; ++nf) {
                int n = n0 + nf * 16 + lr;
                float bias = bih[n] + bhh[n];
                int gate = n >> 10, hc = n & 1023;
#pragma unroll
                for (int q = 0; q < 4; ++q) {
                    int rr = r0 + lq * 4 + q;
                    if (rr < 2016)
                        stg_u16(&xg2[((size_t)rr * 1024 + hc) * 4 + gate], f2bf(acc[nf][q] + bias));
                }
            }
        } else {
            const int mb = tile - 2048;
            const int mt = mb & 63, nt = mb >> 6;
            const int r0 = mt * 64 + wv * 16, n0 = nt * 64;
            const u16* arow = enc16 + (size_t)(r0 + lr) * 1024;
            const u16* brow = WT + (size_t)(n0 + lr) * 1024;
            f32x4 acc[4] = {{0,0,0,0},{0,0,0,0},{0,0,0,0},{0,0,0,0}};
            for (int k0 = 0; k0 < 1024; k0 += 32) {
                int ko = k0 + lq * 8;
                short8 av = *(const short8*)(arow + ko);
#pragma unroll
                for (int nf = 0; nf < 4; ++nf) {
                    short8 bv = *(const short8*)(brow + (size_t)nf * 16 * 1024 + ko);
                    acc[nf] = __builtin_amdgcn_mfma_f32_16x16x32_bf16(av, bv, acc[nf], 0, 0, 0);
                }
            }
#pragma unroll
            for (int nf = 0; nf < 4; ++nf) {
                int n = n0 + nf * 16 + lr;
#pragma unroll
                for (int q = 0; q < 4; ++q)
                    stg_f32(&Mf[(size_t)(r0 + lq * 4 + q) * 1024 + n], acc[nf][q]);
            }
        }
    }
    bar_post(slots, 2, bid, tid);
    bar_wait256(slots, 2, tid);

    // ================= serial loop =================
    if (bid < 64) {
        // -------- group A: gates GEMM + LSTM, 64-block barrier domain --------
        const int g = bid;
        // stage W_hh -> LDS (swizzled), rows n=gate*16+j
        for (int u = tid; u < 8192; u += 256) {
            int row = u >> 7, c16 = u & 127;
            const float* src = Whh + ((size_t)((row >> 4) * 1024 + g * 16 + (row & 15))) * 1024 + c16 * 8;
            short8 w = cvt8(src);
            int byte = (row * 2048 + c16 * 16) ^ ((row & 7) << 4);
            *(short8*)(smem + byte) = w;
        }
        // LSTM locals: thread -> cells (b, jp), (b, jp+1); hc = g*16+jp
        const int b = tid >> 3, jp = (tid & 7) * 2;
        const int hc = g * 16 + jp;
        float creg0 = (hc < 512) ? c0[(size_t)b * 512 + hc] : c0[(size_t)(32 + b) * 512 + hc - 512];
        float creg1 = (hc + 1 < 512) ? c0[(size_t)b * 512 + hc + 1] : c0[(size_t)(32 + b) * 512 + hc + 1 - 512];
        float xga[4], xgb[4];
        {
            f32x4 raw = *(const f32x4*)(xg2 + ((size_t)b * 1024 + hc) * 4);   // t=0
            union { f32x4 f; short8 s; } u; u.f = raw;
#pragma unroll
            for (int gt = 0; gt < 4; ++gt) { xga[gt] = bf2f((u16)u.s[gt]); xgb[gt] = bf2f((u16)u.s[4 + gt]); }
        }
        const int kw = wv & 1, nw = wv >> 1;       // K-half, N-half per wave
        __syncthreads();

        for (int t = 0; t < 63; ++t) {
            if (t > 0) bar_wait64(slots, (u32)(t + 2), tid);

            // ---- GEMM: 32 batches x 64 gate-cols, K=1024 (this wave: K-half kw, N-half nw)
            const u16* hbase = hb + (size_t)(t & 1) * 32768;
            const u16* p0 = hbase + (size_t)lr * 1024 + kw * 512 + lq * 8;
            const u16* p1 = p0 + 16 * 1024;
            i32x4 ap0[8], ap1[8];
#pragma unroll
            for (int p = 0; p < 8; ++p) { ldcc4i(&ap0[p], p0 + p * 32); ldcc4i(&ap1[p], p1 + p * 32); }
            f32x4 acc00 = {0,0,0,0}, acc01 = {0,0,0,0}, acc10 = {0,0,0,0}, acc11 = {0,0,0,0};
#pragma unroll
            for (int ks = 0; ks < 16; ++ks) {
                // B frags from swizzled LDS
                int n0r = nw * 32 + lr;
                int kbyte = (kw * 512 + ks * 32 + lq * 8) * 2;
                short8 bv0 = *(const short8*)(smem + ((n0r * 2048 + kbyte) ^ ((n0r & 7) << 4)));
                int n1r = n0r + 16;
                short8 bv1 = *(const short8*)(smem + ((n1r * 2048 + kbyte) ^ ((n1r & 7) << 4)));
                if (ks <= 8) { asm volatile("s_waitcnt vmcnt(14)" ::: "memory"); }
                else         { asm volatile("s_waitcnt vmcnt(%0)" :: "i"(2 * (15 - ks)) : "memory"); }
                __builtin_amdgcn_sched_barrier(0);
                short8 a0 = as_s8(ap0[ks & 7]), a1 = as_s8(ap1[ks & 7]);
                acc00 = __builtin_amdgcn_mfma_f32_16x16x32_bf16(a0, bv0, acc00, 0, 0, 0);
                acc10 = __builtin_amdgcn_mfma_f32_16x16x32_bf16(a1, bv0, acc10, 0, 0, 0);
                acc01 = __builtin_amdgcn_mfma_f32_16x16x32_bf16(a0, bv1, acc01, 0, 0, 0);
                acc11 = __builtin_amdgcn_mfma_f32_16x16x32_bf16(a1, bv1, acc11, 0, 0, 0);
                if (ks < 8) { ldcc4i(&ap0[ks & 7], p0 + (ks + 8) * 32); ldcc4i(&ap1[ks & 7], p1 + (ks + 8) * 32); }
            }
#pragma unroll
            for (int q = 0; q < 4; ++q) {
                red[(kw * 32 + lq * 4 + q) * RED_PITCH + nw * 32 + lr]       = acc00[q];
                red[(kw * 32 + 16 + lq * 4 + q) * RED_PITCH + nw * 32 + lr]  = acc10[q];
                red[(kw * 32 + lq * 4 + q) * RED_PITCH + nw * 32 + 16 + lr]      = acc01[q];
                red[(kw * 32 + 16 + lq * 4 + q) * RED_PITCH + nw * 32 + 16 + lr] = acc11[q];
            }
            __syncthreads();

            // ---- LSTM (2 cells/thread)
            float G0[4], G1[4];
#pragma unroll
            for (int gt = 0; gt < 4; ++gt) {
                int n = gt * 16 + jp;
                G0[gt] = red[b * RED_PITCH + n] + red[(32 + b) * RED_PITCH + n] + xga[gt];
                G1[gt] = red[b * RED_PITCH + n + 1] + red[(32 + b) * RED_PITCH + n + 1] + xgb[gt];
            }
            float cn0 = sigm(G0[1]) * creg0 + sigm(G0[0]) * tanhf(G0[2]);
            float hn0 = sigm(G0[3]) * tanhf(cn0);
            float cn1 = sigm(G1[1]) * creg1 + sigm(G1[0]) * tanhf(G1[2]);
            float hn1 = sigm(G1[3]) * tanhf(cn1);
            creg0 = cn0; creg1 = cn1;
            u16 hb0 = f2bf(hn0), hb1 = f2bf(hn1);
            u32 hpair = (u32)hb0 | ((u32)hb1 << 16);
            stg_u32((u32*)&hb[(size_t)((t + 1) & 1) * 32768 + b * 1024 + hc], hpair);
            stg_u32((u32*)&hAll[((size_t)t * 32 + b) * 1024 + hc], hpair);
            stg_u64((u64*)&hAllF[((size_t)t * 32 + b) * 1024 + hc], pack2f(hn0, hn1));
            if (t == 62)
                stg_u64((u64*)&out[2064384 + b * 1024 + hc], pack2f(hn0, hn1));

            bar_post(slots, (u32)(t + 3), bid, tid);
            __syncthreads();   // red reuse protection

            // shadow: prefetch next xg
            if (t < 62) {
                f32x4 raw = *(const f32x4*)(xg2 + ((size_t)((t + 1) * 32 + b) * 1024 + hc) * 4);
                union { f32x4 f; short8 s; } u; u.f = raw;
#pragma unroll
                for (int gt = 0; gt < 4; ++gt) { xga[gt] = bf2f((u16)u.s[gt]); xgb[gt] = bf2f((u16)u.s[4 + gt]); }
            }
        }
        // final c
        stg_u64((u64*)&out[2064384 + 32768 + b * 1024 + hc], pack2f(creg0, creg1));
    } else if (bid < 192) {
        // -------- group B: attention chunks, no barrier (trails group A) --------
        const int idx = bid - 64;
        const int b = idx >> 2, q = idx & 3;
        int vlen = slen[b]; if (vlen < 1) vlen = 1;
        const int tj = l & 15, sg4 = l >> 4;
        // stage this chunk's 32 Mf rows -> LDS (fp32, pitch 1032: conflict-free)
        for (int u = tid; u < 8192; u += 256) {
            int row = u >> 8, c = (u & 255) * 4;
            *(f32x4*)(MlB + row * MLB_PITCH + c) =
                *(const f32x4*)(Mf + ((size_t)(b * 128 + q * 32 + row)) * 1024 + c);
        }
        __syncthreads();
        for (int s = 0; s < 63; ++s) {
            bar_wait64(slots, (u32)(s + 3), tid);       // h_{s+1} visible
            {   // stage h into LDS
                f32x4 hv;
                ldcc4f(&hv, hAllF + ((size_t)s * 32 + b) * 1024 + tid * 4);
                asm volatile("s_waitcnt vmcnt(0)" ::: "memory");
                __builtin_amdgcn_sched_barrier(0);
                *(f32x4*)&hB[tid * 4] = hv;
            }
            __syncthreads();
            // scores: wave wv rows [wv*8, wv*8+8)
#pragma unroll
            for (int rr2 = 0; rr2 < 2; ++rr2) {
                int lrow = wv * 8 + rr2 * 4 + sg4;
                const float* Mrow = MlB + (size_t)lrow * MLB_PITCH;
                float sc = 0.f;
#pragma unroll
                for (int it = 0; it < 16; ++it) {
                    int j = it * 64 + tj * 4;
                    f32x4 m4 = *(const f32x4*)(Mrow + j);
                    f32x4 h4 = *(const f32x4*)&hB[j];
                    sc += m4[0]*h4[0] + m4[1]*h4[1] + m4[2]*h4[2] + m4[3]*h4[3];
                }
                sc += __shfl_xor(sc, 1);
                sc += __shfl_xor(sc, 2);
                sc += __shfl_xor(sc, 4);
                sc += __shfl_xor(sc, 8);
                if (tj == 0) scb[lrow] = (q * 32 + lrow < vlen) ? sc : -1e30f;
            }
            __syncthreads();
            if (tid < 64) {   // wave0: chunk partial softmax
                float a = (tid < 32) ? scb[tid] : -1e30f;
                float m = a;
#pragma unroll
                for (int d = 1; d < 64; d <<= 1) m = fmaxf(m, __shfl_xor(m, d));
                float e = (tid < 32 && a > -1e29f) ? expf(a - m) : 0.f;
                float ssum = e;
#pragma unroll
                for (int d = 1; d < 64; d <<= 1) ssum += __shfl_xor(ssum, d);
                if (tid < 32) pb[tid] = e;
                if (tid == 0) {
                    stg_f32(&pMx[((size_t)s * 32 + b) * 4 + q], m);
                    stg_f32(&pSm[((size_t)s * 32 + b) * 4 + q], ssum);
                }
            }
            __syncthreads();
            // ctx partial (unnormalized)
            f32x4 ca = {0.f, 0.f, 0.f, 0.f};
            const u16* eb = enc16 + ((size_t)(b * 128 + q * 32)) * 1024 + tid * 4;
#pragma unroll
            for (int r = 0; r < 32; ++r) {
                float p = pb[r];
                short4v e4 = *(const short4v*)(eb + (size_t)r * 1024);
                ca[0] += p * bf2f((u16)e4[0]);
                ca[1] += p * bf2f((u16)e4[1]);
                ca[2] += p * bf2f((u16)e4[2]);
                ca[3] += p * bf2f((u16)e4[3]);
            }
            stcc4f(pCtx + (((size_t)s * 32 + b) * 4 + q) * 1024 + tid * 4, ca);
        }
    }
    bar_post(slots, 66, bid, tid);
    bar_wait256(slots, 66, tid);

    // ================= P2a: combine chunk partials -> ctxA =================
    for (int r = bid; r < 2016; r += 256) {
        float m4[4], s4[4];
#pragma unroll
        for (int c = 0; c < 4; ++c) { m4[c] = ldg_f32(pMx + (size_t)r * 4 + c); s4[c] = ldg_f32(pSm + (size_t)r * 4 + c); }
        float gm = fmaxf(fmaxf(m4[0], m4[1]), fmaxf(m4[2], m4[3]));
        float e[4], ws = 0.f;
#pragma unroll
        for (int c = 0; c < 4; ++c) { e[c] = expf(m4[c] - gm); ws += s4[c] * e[c]; }
        float inv = 1.f / ws;
        f32x4 pc[4];
#pragma unroll
        for (int c = 0; c < 4; ++c) ldcc4f(&pc[c], pCtx + ((size_t)r * 4 + c) * 1024 + tid * 4);
        asm volatile("s_waitcnt vmcnt(0)" ::: "memory");
        __builtin_amdgcn_sched_barrier(0);
        f32x4 a = {0.f, 0.f, 0.f, 0.f};
#pragma unroll
        for (int c = 0; c < 4; ++c) {
            float sc = e[c] * inv;
            a[0] += pc[c][0] * sc; a[1] += pc[c][1] * sc; a[2] += pc[c][2] * sc; a[3] += pc[c][3] * sc;
        }
        stg_u64((u64*)(ctxA + (size_t)r * 1024 + tid * 4), pack4bf(a));
    }
    bar_post(slots, 67, bid, tid);
    bar_wait256(slots, 67, tid);

    // ================= P2b: output GEMM (512 tiles, 2 per block) =================
    for (int tile = bid; tile < 512; tile += 256) {
        const int mt = tile & 31, nt = tile >> 5;
        const int r0 = mt * 64 + wv * 16, n0 = nt * 64;
        int rr0 = r0 + lr; int rc = (rr0 < 2016) ? rr0 : 2015;
        const u16* arc = ctxA + (size_t)rc * 1024;
        const u16* arh = hAll + (size_t)rc * 1024;
        const u16* brow = Wao16 + (size_t)(n0 + lr) * 2048;
        f32x4 acc[4] = {{0,0,0,0},{0,0,0,0},{0,0,0,0},{0,0,0,0}};
        for (int k0 = 0; k0 < 2048; k0 += 32) {
            int ko = k0 + lq * 8;
            short8 av = (k0 < 1024) ? *(const short8*)(arc + ko)
                                    : *(const short8*)(arh + (ko - 1024));
#pragma unroll
            for (int nf = 0; nf < 4; ++nf) {
                short8 bv = *(const short8*)(brow + (size_t)nf * 16 * 2048 + ko);
                acc[nf] = __builtin_amdgcn_mfma_f32_16x16x32_bf16(av, bv, acc[nf], 0, 0, 0);
            }
        }
#pragma unroll
        for (int nf = 0; nf < 4; ++nf) {
            int n = n0 + nf * 16 + lr;
#pragma unroll
            for (int q = 0; q < 4; ++q) {
                int rr = r0 + lq * 4 + q;
                if (rr < 2016) {
                    int t = rr >> 5, b = rr & 31;
                    out[(size_t)b * 64512 + t * 1024 + n] = tanhf(acc[nf][q]);
                }
            }
        }
    }
}

// ---------------------------------------------------------------------------
extern "C" void kernel_launch(void* const* d_in, const int* in_sizes, int n_in,
                              void* d_out, int out_size, void* d_ws, size_t ws_size,
                              hipStream_t stream)
{
    (void)in_sizes; (void)n_in; (void)out_size; (void)ws_size;
    const int*   tgt  = (const int*)d_in[0];
    const float* h0   = (const float*)d_in[1];
    const float* c0   = (const float*)d_in[2];
    const float* enc  = (const float*)d_in[3];
    const int*   slen = (const int*)d_in[4];
    const float* emb  = (const float*)d_in[5];
    const float* Wih  = (const float*)d_in[6];
    const float* Whh  = (const float*)d_in[7];
    const float* bih  = (const float*)d_in[8];
    const float* bhh  = (const float*)d_in[9];
    const float* Wai  = (const float*)d_in[10];
    const float* Wao  = (const float*)d_in[11];
    float* out = (float*)d_out;

    char* ws = (char*)d_ws;
    size_t off = 0;
    auto alloc = [&](size_t bytes) -> char* {
        char* p = ws + off; off += (bytes + 255) & ~(size_t)255; return p;
    };
    u16*   Wih16 = (u16*)  alloc(4096UL * 1024 * 2);
    u16*   Wao16 = (u16*)  alloc(1024UL * 2048 * 2);
    u16*   enc16 = (u16*)  alloc(4096UL * 1024 * 2);
    u16*   xrow  = (u16*)  alloc(2016UL * 1024 * 2);
    u16*   WT    = (u16*)  alloc(1024UL * 1024 * 2);
    u16*   xg2   = (u16*)  alloc(2016UL * 1024 * 4 * 2);
    float* Mf    = (float*)alloc(4096UL * 1024 * 4);
    u16*   hb    = (u16*)  alloc(2UL * 32 * 1024 * 2);
    float* hAllF = (float*)alloc(2016UL * 1024 * 4);
    u16*   hAll  = (u16*)  alloc(2016UL * 1024 * 2);
    u16*   ctxA  = (u16*)  alloc(2016UL * 1024 * 2);
    float* pCtx  = (float*)alloc(2016UL * 4 * 1024 * 4);
    float* pMx   = (float*)alloc(2016UL * 4 * 4);
    float* pSm   = (float*)alloc(2016UL * 4 * 4);
    u32*   bar   = (u32*)  alloc(2048);

    static int lds_set = 0;
    if (!lds_set) {
        (void)hipFuncSetAttribute((const void*)k_all,
                                  hipFuncAttributeMaxDynamicSharedMemorySize, DYN_BYTES);
        lds_set = 1;
    }

    hipMemsetAsync(bar, 0, 2048, stream);
    void* kargs[] = { (void*)&tgt, (void*)&h0, (void*)&c0, (void*)&enc, (void*)&slen, (void*)&emb,
                      (void*)&Wih, (void*)&Whh, (void*)&bih, (void*)&bhh, (void*)&Wai, (void*)&Wao,
                      (void*)&out,
                      (void*)&Wih16, (void*)&Wao16, (void*)&enc16, (void*)&xrow, (void*)&WT,
                      (void*)&xg2, (void*)&Mf, (void*)&hb, (void*)&hAllF, (void*)&hAll, (void*)&ctxA,
                      (void*)&pCtx, (void*)&pMx, (void*)&pSm, (void*)&bar };
    hipLaunchCooperativeKernel((const void*)k_all, dim3(256), dim3(256), kargs, DYN_BYTES, stream);
}